// Round 7
// baseline (446.217 us; speedup 1.0000x reference)
//
#include <hip/hip_runtime.h>
#include <math.h>

// Problem constants
#define S_ 500
#define D_ 768
#define K_ 16
#define R_ 256
#define P_ 64
#define NT 12  // 768 / BK, BK = 64
#define NBLK 512

typedef unsigned short ushort_t;
typedef __attribute__((ext_vector_type(8))) short short8;   // 8 x bf16 (4 VGPRs)
typedef __attribute__((ext_vector_type(4))) float floatx4;  // MFMA accumulator

__device__ inline ushort_t f2bf(float x) {  // fp32 -> bf16, round-nearest-even
  unsigned int u = __float_as_uint(x);
  u += 0x7fffu + ((u >> 16) & 1u);
  return (ushort_t)(u >> 16);
}

#define GLD_LDS16(g, l)                                                        \
  __builtin_amdgcn_global_load_lds(                                            \
      (const __attribute__((address_space(1))) void*)(g),                      \
      (__attribute__((address_space(3))) void*)(l), 16, 0, 0)

#define ASM_BARRIER asm volatile("s_barrier" ::: "memory")
#define WAIT_VM8 asm volatile("s_waitcnt vmcnt(8)" ::: "memory")
#define WAIT_VM6 asm volatile("s_waitcnt vmcnt(6)" ::: "memory")
#define WAIT_VM0 asm volatile("s_waitcnt vmcnt(0)" ::: "memory")

// device-scope phase flags (zeroed via hipMemsetAsync each launch)
__device__ __forceinline__ void phase_arrive(int* f) {
  __syncthreads();      // all block's work issued
  __threadfence();      // release: writeback so other XCDs see our stores
  if (threadIdx.x == 0) atomicAdd(f, 1);
}
__device__ __forceinline__ void phase_wait(int* f, int target) {
  if (threadIdx.x == 0) {
    while (__hip_atomic_load(f, __ATOMIC_RELAXED, __HIP_MEMORY_SCOPE_AGENT) < target)
      __builtin_amdgcn_s_sleep(2);
  }
  __syncthreads();
  __threadfence();      // acquire: invalidate stale L1/L2 lines
}

// ---------------------------------------------------------------------------
// Fused persistent kernel: prep -> mm0 -> mm1 -> lse, 512 blocks = 2/CU exact.
// flags[0]: prep done (512) | flags[1+r], r<4: mm0 row-r tiles done (96 each)
// flags[5]: mm1 done (512)
// ---------------------------------------------------------------------------
__global__ __launch_bounds__(256, 2) void fused(
    const float* __restrict__ WE, const float* __restrict__ W,
    const int* __restrict__ idx1, const int* __restrict__ idx2,
    const float* __restrict__ mask1, const float* __restrict__ mask2,
    ushort_t* __restrict__ WEb, ushort_t* __restrict__ Wt,
    ushort_t* __restrict__ projb, ushort_t* __restrict__ G,
    int* __restrict__ flags, float* __restrict__ out) {
  __shared__ __align__(16) char smem[65536];
  const int bid = blockIdx.x;
  const int tid = threadIdx.x;
  const int wave = tid >> 6, lane = tid & 63;
  const int col = lane & 15, quad = lane >> 4;

  // ======== phase 0: prep (grid-strided over 2688 units) ========
  {
    float(*tile)[68] = (float(*)[68])smem;  // 17.4 KB
    for (int u = bid; u < 2688; u += NBLK) {
      if (u < 384) {  // WE fp32 [500][768] -> WEb bf16 [512][768], pad = 0
        int gid = u * 256 + tid;
        int row = gid / 192;
        ushort4 o = {0, 0, 0, 0};
        if (row < S_) {
          float4 v = *(const float4*)(WE + (size_t)gid * 4);
          o.x = f2bf(v.x); o.y = f2bf(v.y); o.z = f2bf(v.z); o.w = f2bf(v.w);
        }
        *(ushort4*)(WEb + (size_t)gid * 4) = o;
      } else {  // W fp32 [768][12288] -> Wt bf16 [12288][768], 64x64 tiles
        int tb = u - 384;
        int n0 = (tb % 192) * 64, d0 = (tb / 192) * 64;
        __syncthreads();  // previous unit's tile reads done
        {
          const int r = tid >> 2, cbase = (tid & 3) * 16;
#pragma unroll
          for (int i = 0; i < 4; i++) {
            float4 v = *(const float4*)(W + (size_t)(d0 + r) * 12288 + n0 + cbase + i * 4);
            *(float4*)&tile[r][cbase + i * 4] = v;
          }
        }
        __syncthreads();
        {
          const int bc = tid & 15, br4 = (tid >> 4) * 4;
          float4 tv[4];
#pragma unroll
          for (int ii = 0; ii < 4; ii++)
            tv[ii] = *(const float4*)&tile[bc * 4 + ii][br4];
#pragma unroll
          for (int j = 0; j < 4; j++) {
            ushort4 o;
            o.x = f2bf(((const float*)&tv[0])[j]);
            o.y = f2bf(((const float*)&tv[1])[j]);
            o.z = f2bf(((const float*)&tv[2])[j]);
            o.w = f2bf(((const float*)&tv[3])[j]);
            *(ushort4*)(Wt + (size_t)(n0 + br4 + j) * 768 + d0 + bc * 4) = o;
          }
        }
      }
    }
  }
  phase_arrive(&flags[0]);
  phase_wait(&flags[0], NBLK);

  // ======== phase 1: mm0 = WEb @ Wt^T (blocks 0..383, R4 config) ========
  // Tile 128x128, BK=64 dbuf, 64 KB LDS. mfma(b,a) -> col-run ushort4 stores.
  if (bid < 384) {
    typedef ushort_t buf128[2][2][128 * 32];
    buf128& As = *(buf128*)smem;             // 32 KB
    buf128& Bs = *(buf128*)(smem + 32768);   // 32 KB
    const int bx = bid % 96, by = bid / 96;
    const int m0 = by * 128, n0 = bx * 128;
    const int wm = (wave & 1) * 64, wn = (wave >> 1) * 64;

    floatx4 acc[4][4];
#pragma unroll
    for (int i = 0; i < 4; i++)
#pragma unroll
      for (int j = 0; j < 4; j++)
#pragma unroll
        for (int e = 0; e < 4; e++) acc[i][j][e] = 0.f;

    const int srow = wave * 32 + (lane >> 2);
    const int scol = (lane & 3) * 8;
    const ushort_t* ga0 = WEb + (size_t)(m0 + srow) * D_ + scol;
    const ushort_t* gb0 = Wt + (size_t)(n0 + srow) * D_ + scol;
    const int ldsbase = (wave * 32) * 32;

#define ISSUE_TILE0(t_, buf_)                                                  \
  do {                                                                         \
    const ushort_t* ga = ga0 + (t_)*64;                                        \
    const ushort_t* gb = gb0 + (t_)*64;                                        \
    GLD_LDS16(ga, &As[buf_][0][ldsbase]);                                      \
    GLD_LDS16(ga + 16 * D_, &As[buf_][0][ldsbase + 16 * 32]);                  \
    GLD_LDS16(ga + 32, &As[buf_][1][ldsbase]);                                 \
    GLD_LDS16(ga + 32 + 16 * D_, &As[buf_][1][ldsbase + 16 * 32]);             \
    GLD_LDS16(gb, &Bs[buf_][0][ldsbase]);                                      \
    GLD_LDS16(gb + 16 * D_, &Bs[buf_][0][ldsbase + 16 * 32]);                  \
    GLD_LDS16(gb + 32, &Bs[buf_][1][ldsbase]);                                 \
    GLD_LDS16(gb + 32 + 16 * D_, &Bs[buf_][1][ldsbase + 16 * 32]);             \
  } while (0)

    ISSUE_TILE0(0, 0);
    for (int t = 0; t < NT; ++t) {
      const int cur = t & 1;
      if (t + 1 < NT) {
        ISSUE_TILE0(t + 1, cur ^ 1);
        WAIT_VM8;
      } else {
        WAIT_VM0;
      }
      ASM_BARRIER;
#pragma unroll
      for (int s = 0; s < 2; ++s) {
        short8 a[4], b[4];
#pragma unroll
        for (int i = 0; i < 4; i++)
          a[i] = *(const short8*)&As[cur][s][(wm + i * 16 + col) * 32 + quad * 8];
#pragma unroll
        for (int j = 0; j < 4; j++)
          b[j] = *(const short8*)&Bs[cur][s][(wn + j * 16 + col) * 32 + quad * 8];
#pragma unroll
        for (int i = 0; i < 4; i++)
#pragma unroll
          for (int j = 0; j < 4; j++)
            acc[i][j] = __builtin_amdgcn_mfma_f32_16x16x32_bf16(b[j], a[i], acc[i][j], 0, 0, 0);
      }
      ASM_BARRIER;
    }
#undef ISSUE_TILE0

#pragma unroll
    for (int i = 0; i < 4; i++) {
      int m = m0 + wm + i * 16 + col;
#pragma unroll
      for (int j = 0; j < 4; j++) {
        int n = n0 + wn + j * 16 + quad * 4;
        ushort4 o;
        o.x = f2bf(acc[i][j][0]); o.y = f2bf(acc[i][j][1]);
        o.z = f2bf(acc[i][j][2]); o.w = f2bf(acc[i][j][3]);
        *(ushort4*)(projb + (size_t)m * 12288 + n) = o;
      }
    }
    phase_arrive(&flags[1 + by]);  // row-by producer count (target 96)
  }

  // ======== phase 2: mm1 = projb @ WEb^T (all 512 blocks) ========
  // Tile 128m x 64n. Needs only proj row-block r = mby>>4 -> fine-grained wait.
  {
    typedef ushort_t abuf[2][2][128 * 32];  // 32 KB
    typedef ushort_t bbuf[2][2][64 * 32];   // 16 KB
    abuf& As = *(abuf*)smem;
    bbuf& Bs = *(bbuf*)(smem + 32768);
    const int mby = bid >> 3, mbx = bid & 7;
    const int m0 = mby * 128, n0 = mbx * 64;
    const int wm = (wave & 1) * 64, wn = (wave >> 1) * 32;

    phase_wait(&flags[1 + (mby >> 4)], 96);  // my proj rows are complete

    floatx4 acc[4][2];
#pragma unroll
    for (int i = 0; i < 4; i++)
#pragma unroll
      for (int j = 0; j < 2; j++)
#pragma unroll
        for (int e = 0; e < 4; e++) acc[i][j][e] = 0.f;

    const int lrow = lane >> 2, scol = (lane & 3) * 8;
    const ushort_t* ga0 = projb + (size_t)(m0 + wave * 32 + lrow) * D_ + scol;
    const ushort_t* gb0 = WEb + (size_t)(n0 + wave * 16 + lrow) * D_ + scol;
    const int aoff = (wave * 32) * 32;
    const int boff = (wave * 16) * 32;

#define ISSUE_TILE1(t_, buf_)                                                  \
  do {                                                                         \
    _Pragma("unroll") for (int s_ = 0; s_ < 2; s_++) {                         \
      const ushort_t* ga = ga0 + (t_)*64 + s_ * 32;                            \
      const ushort_t* gb = gb0 + (t_)*64 + s_ * 32;                            \
      GLD_LDS16(ga, &As[buf_][s_][aoff]);                                      \
      GLD_LDS16(ga + 16 * D_, &As[buf_][s_][aoff + 16 * 32]);                  \
      GLD_LDS16(gb, &Bs[buf_][s_][boff]);                                      \
    }                                                                          \
  } while (0)

    ISSUE_TILE1(0, 0);
    for (int t = 0; t < NT; ++t) {
      const int cur = t & 1;
      if (t + 1 < NT) {
        ISSUE_TILE1(t + 1, cur ^ 1);
        WAIT_VM6;
      } else {
        WAIT_VM0;
      }
      ASM_BARRIER;
#pragma unroll
      for (int s = 0; s < 2; ++s) {
        short8 a[4], b[2];
#pragma unroll
        for (int i = 0; i < 4; i++)
          a[i] = *(const short8*)&As[cur][s][(wm + i * 16 + col) * 32 + quad * 8];
#pragma unroll
        for (int j = 0; j < 2; j++)
          b[j] = *(const short8*)&Bs[cur][s][(wn + j * 16 + col) * 32 + quad * 8];
#pragma unroll
        for (int i = 0; i < 4; i++)
#pragma unroll
          for (int j = 0; j < 2; j++)
            acc[i][j] = __builtin_amdgcn_mfma_f32_16x16x32_bf16(a[i], b[j], acc[i][j], 0, 0, 0);
      }
      ASM_BARRIER;
    }
#undef ISSUE_TILE1

#pragma unroll
    for (int i = 0; i < 4; i++) {
      int s1 = (m0 + wm + i * 16) >> 4;
#pragma unroll
      for (int j = 0; j < 2; j++) {
        int s2 = n0 + wn + j * 16 + col;
        if (s1 < S_ && s2 < S_) {
          ushort4 o;
          o.x = f2bf(acc[i][j][0]); o.y = f2bf(acc[i][j][1]);
          o.z = f2bf(acc[i][j][2]); o.w = f2bf(acc[i][j][3]);
          *(ushort4*)(G + (((size_t)s1 * S_ + s2) << 4) + quad * 4) = o;
        }
      }
    }
  }
  phase_arrive(&flags[5]);

  // ======== phase 3: lse (blocks 0..255, one r each) ========
  if (bid >= 256) return;
  phase_wait(&flags[5], NBLK);  // all of G visible
  {
    int* b1 = (int*)smem;                      // [64]
    int* b2 = b1 + P_;                         // [64]
    float* wmx = (float*)(b2 + P_);            // [4][16]
    float* wsum = wmx + 4 * K_;                // [4][16]
    int* slen = (int*)(wsum + 4 * K_);         // [2]
    const int r = bid;

    if (tid < 64) {
      float mv = mask1[r * P_ + tid];
      unsigned long long bal = __ballot(mv > 0.5f);
      if (tid == 0) slen[0] = (int)__popcll(bal);
      b1[tid] = idx1[r * P_ + tid] * (S_ * K_);
    } else if (tid < 128) {
      int q = tid - 64;
      float mv = mask2[r * P_ + q];
      unsigned long long bal = __ballot(mv > 0.5f);
      if (q == 0) slen[1] = (int)__popcll(bal);
      b2[q] = idx2[r * P_ + q] * K_;
    }
    __syncthreads();
    const int len2 = slen[1];
    const int total = slen[0] * len2;

    float m[K_], s[K_];
#pragma unroll
    for (int k = 0; k < K_; k++) { m[k] = -3.0e38f; s[k] = 0.f; }

    for (int i = tid; i < total; i += 256) {
      int p = i / len2;
      int q = i - p * len2;
      const uint4* g4 = (const uint4*)(G + b1[p] + b2[q]);  // 16 bf16 = 32 B
      uint4 w0 = g4[0], w1 = g4[1];
      unsigned int uu[8] = {w0.x, w0.y, w0.z, w0.w, w1.x, w1.y, w1.z, w1.w};
      float z[K_];
#pragma unroll
      for (int h = 0; h < 8; h++) {
        z[2 * h + 0] = __uint_as_float(uu[h] << 16);
        z[2 * h + 1] = __uint_as_float(uu[h] & 0xffff0000u);
      }
#pragma unroll
      for (int k = 0; k < K_; k++) {
        float zk = z[k];
        float M2 = fmaxf(m[k], zk);
        s[k] = s[k] * __expf(m[k] - M2) + __expf(zk - M2);
        m[k] = M2;
      }
    }

#pragma unroll
    for (int off = 1; off < 64; off <<= 1) {
#pragma unroll
      for (int k = 0; k < K_; k++) {
        float mo = __shfl_xor(m[k], off, 64);
        float so = __shfl_xor(s[k], off, 64);
        float M2 = fmaxf(m[k], mo);
        s[k] = s[k] * __expf(m[k] - M2) + so * __expf(mo - M2);
        m[k] = M2;
      }
    }
    if (lane == 0) {
#pragma unroll
      for (int k = 0; k < K_; k++) { wmx[wave * K_ + k] = m[k]; wsum[wave * K_ + k] = s[k]; }
    }
    __syncthreads();
    if (tid < K_) {
      float M = -3.0e38f, Ssum = 0.f;
#pragma unroll
      for (int w = 0; w < 4; w++) {
        float mo = wmx[w * K_ + tid], so = wsum[w * K_ + tid];
        float M2 = fmaxf(M, mo);
        Ssum = Ssum * __expf(M - M2) + so * __expf(mo - M2);
        M = M2;
      }
      out[r * K_ + tid] = M + __logf(Ssum);
    }
  }
}

// ---------------------------------------------------------------------------
extern "C" void kernel_launch(void* const* d_in, const int* in_sizes, int n_in,
                              void* d_out, int out_size, void* d_ws, size_t ws_size,
                              hipStream_t stream) {
  const float* WE    = (const float*)d_in[0];  // [500][768]
  const float* W     = (const float*)d_in[1];  // [768][16][768]
  const int*   idx1  = (const int*)d_in[2];
  const int*   idx2  = (const int*)d_in[3];
  const float* mask1 = (const float*)d_in[4];
  const float* mask2 = (const float*)d_in[5];
  float* out = (float*)d_out;                  // [256][16]

  // workspace: flags (256 B) | WEb [512][768] bf16 | Wt [12288][768] bf16 |
  //            projb [512][12288] bf16 (== [8192][768]) | G [500][500][16] bf16
  int*      flags = (int*)d_ws;
  ushort_t* WEb   = (ushort_t*)((char*)d_ws + 256);
  ushort_t* Wt    = WEb + (size_t)512 * 768;
  ushort_t* projb = Wt + (size_t)12288 * 768;
  ushort_t* G     = projb + (size_t)8192 * 768;
  // total ~40.3 MB, 16B-aligned throughout

  hipMemsetAsync(flags, 0, 64, stream);  // zero phase flags (graph memset node)
  fused<<<NBLK, 256, 0, stream>>>(WE, W, idx1, idx2, mask1, mask2,
                                  WEb, Wt, projb, G, flags, out);
}

// Round 8
// 142.964 us; speedup vs baseline: 3.1212x; 3.1212x over previous
//
#include <hip/hip_runtime.h>
#include <math.h>

// Problem constants
#define S_ 500
#define D_ 768
#define K_ 16
#define R_ 256
#define P_ 64
#define NT 12  // 768 / BK, BK = 64

typedef unsigned short ushort_t;
typedef __attribute__((ext_vector_type(8))) short short8;   // 8 x bf16 (4 VGPRs)
typedef __attribute__((ext_vector_type(4))) float floatx4;  // MFMA accumulator

__device__ inline ushort_t f2bf(float x) {  // fp32 -> bf16, round-nearest-even
  unsigned int u = __float_as_uint(x);
  u += 0x7fffu + ((u >> 16) & 1u);
  return (ushort_t)(u >> 16);
}

#define GLD_LDS16(g, l)                                                        \
  __builtin_amdgcn_global_load_lds(                                            \
      (const __attribute__((address_space(1))) void*)(g),                      \
      (__attribute__((address_space(3))) void*)(l), 16, 0, 0)

// raw barrier / fine-grained vmcnt: no compiler-inserted vmcnt(0) drain.
#define ASM_BARRIER asm volatile("s_barrier" ::: "memory")
#define WAIT_VM8 asm volatile("s_waitcnt vmcnt(8)" ::: "memory")
#define WAIT_VM6 asm volatile("s_waitcnt vmcnt(6)" ::: "memory")
#define WAIT_VM0 asm volatile("s_waitcnt vmcnt(0)" ::: "memory")

// ---------------------------------------------------------------------------
// prep: fused convert_we + transpose_w.
//  blocks [0,384):    WE fp32 [500][768] -> WEb bf16 [512][768] (pad rows = 0)
//  blocks [384,2688): W fp32 [768][12288] -> Wt bf16 [12288][768] (64x64 tiles)
// ---------------------------------------------------------------------------
__global__ __launch_bounds__(256) void prep(const float* __restrict__ WE,
                                            const float* __restrict__ W,
                                            ushort_t* __restrict__ WEb,
                                            ushort_t* __restrict__ Wt) {
  const int t = threadIdx.x;
  if (blockIdx.x < 384) {
    int gid = blockIdx.x * 256 + t;  // 98304 threads, 4 elems each
    int row = gid / 192;             // 192 float4 per row
    ushort4 o = {0, 0, 0, 0};
    if (row < S_) {
      float4 v = *(const float4*)(WE + (size_t)gid * 4);
      o.x = f2bf(v.x); o.y = f2bf(v.y); o.z = f2bf(v.z); o.w = f2bf(v.w);
    }
    *(ushort4*)(WEb + (size_t)gid * 4) = o;
    return;
  }
  __shared__ float tile[64][68];
  const int tb = blockIdx.x - 384;          // 0..2303
  const int n0 = (tb % 192) * 64, d0 = (tb / 192) * 64;
  {
    const int r = t >> 2, cbase = (t & 3) * 16;
#pragma unroll
    for (int i = 0; i < 4; i++) {
      float4 v = *(const float4*)(W + (size_t)(d0 + r) * 12288 + n0 + cbase + i * 4);
      *(float4*)&tile[r][cbase + i * 4] = v;
    }
  }
  __syncthreads();
  {
    const int bc = t & 15;
    const int br4 = (t >> 4) * 4;
    float4 tv[4];
#pragma unroll
    for (int ii = 0; ii < 4; ii++)
      tv[ii] = *(const float4*)&tile[bc * 4 + ii][br4];
#pragma unroll
    for (int j = 0; j < 4; j++) {
      ushort4 o;
      o.x = f2bf(((const float*)&tv[0])[j]);
      o.y = f2bf(((const float*)&tv[1])[j]);
      o.z = f2bf(((const float*)&tv[2])[j]);
      o.w = f2bf(((const float*)&tv[3])[j]);
      *(ushort4*)(Wt + (size_t)(n0 + br4 + j) * 768 + d0 + bc * 4) = o;
    }
  }
}

// ---------------------------------------------------------------------------
// mm0_bt: proj = WEb @ Wt^T. Tile 128x128, BK=64 dbuf (2x32-k sub-buffers),
// 64 KB LDS (2 blocks/CU), grid 96x4=384. Raw s_barrier + vmcnt(8): tile
// t+1's 8 loads stay in flight across compute(t).
// mfma(b,a): lane regs span 4 consecutive C-cols -> ushort4 stores.
// C = proj bf16 [512][12288] (== proj2d [8192][768] in memory).
// ---------------------------------------------------------------------------
__global__ __launch_bounds__(256, 2) void mm0_bt(const ushort_t* __restrict__ A,
                                                 const ushort_t* __restrict__ Bm,
                                                 ushort_t* __restrict__ C) {
  __shared__ ushort_t As[2][2][128 * 32];  // [buf][sub][row][32k], 32 KB
  __shared__ ushort_t Bs[2][2][128 * 32];  // 32 KB
  const int tid = threadIdx.x;
  const int wave = tid >> 6, lane = tid & 63;
  const int m0 = blockIdx.y * 128, n0 = blockIdx.x * 128;
  const int wm = (wave & 1) * 64, wn = (wave >> 1) * 64;
  const int col = lane & 15, quad = lane >> 4;

  floatx4 acc[4][4];
#pragma unroll
  for (int i = 0; i < 4; i++)
#pragma unroll
    for (int j = 0; j < 4; j++)
#pragma unroll
      for (int e = 0; e < 4; e++) acc[i][j][e] = 0.f;

  const int srow = wave * 32 + (lane >> 2);  // 16 rows x 16 B per issue
  const int scol = (lane & 3) * 8;
  const ushort_t* ga0 = A + (size_t)(m0 + srow) * D_ + scol;
  const ushort_t* gb0 = Bm + (size_t)(n0 + srow) * D_ + scol;
  const int ldsbase = (wave * 32) * 32;

#define ISSUE_TILE0(t_, buf_)                                                  \
  do {                                                                         \
    const ushort_t* ga = ga0 + (t_)*64;                                        \
    const ushort_t* gb = gb0 + (t_)*64;                                        \
    GLD_LDS16(ga, &As[buf_][0][ldsbase]);                                      \
    GLD_LDS16(ga + 16 * D_, &As[buf_][0][ldsbase + 16 * 32]);                  \
    GLD_LDS16(ga + 32, &As[buf_][1][ldsbase]);                                 \
    GLD_LDS16(ga + 32 + 16 * D_, &As[buf_][1][ldsbase + 16 * 32]);             \
    GLD_LDS16(gb, &Bs[buf_][0][ldsbase]);                                      \
    GLD_LDS16(gb + 16 * D_, &Bs[buf_][0][ldsbase + 16 * 32]);                  \
    GLD_LDS16(gb + 32, &Bs[buf_][1][ldsbase]);                                 \
    GLD_LDS16(gb + 32 + 16 * D_, &Bs[buf_][1][ldsbase + 16 * 32]);             \
  } while (0)

  ISSUE_TILE0(0, 0);
  for (int t = 0; t < NT; ++t) {
    const int cur = t & 1;
    if (t + 1 < NT) {
      ISSUE_TILE0(t + 1, cur ^ 1);
      WAIT_VM8;  // my 8 loads for tile t retired; t+1's stay in flight
    } else {
      WAIT_VM0;
    }
    ASM_BARRIER;
#pragma unroll
    for (int s = 0; s < 2; ++s) {
      short8 a[4], b[4];
#pragma unroll
      for (int i = 0; i < 4; i++)
        a[i] = *(const short8*)&As[cur][s][(wm + i * 16 + col) * 32 + quad * 8];
#pragma unroll
      for (int j = 0; j < 4; j++)
        b[j] = *(const short8*)&Bs[cur][s][(wn + j * 16 + col) * 32 + quad * 8];
#pragma unroll
      for (int i = 0; i < 4; i++)
#pragma unroll
        for (int j = 0; j < 4; j++)
          acc[i][j] = __builtin_amdgcn_mfma_f32_16x16x32_bf16(b[j], a[i], acc[i][j], 0, 0, 0);
    }
    ASM_BARRIER;
  }
#undef ISSUE_TILE0

#pragma unroll
  for (int i = 0; i < 4; i++) {
    int m = m0 + wm + i * 16 + col;
#pragma unroll
    for (int j = 0; j < 4; j++) {
      int n = n0 + wn + j * 16 + quad * 4;
      ushort4 o;
      o.x = f2bf(acc[i][j][0]); o.y = f2bf(acc[i][j][1]);
      o.z = f2bf(acc[i][j][2]); o.w = f2bf(acc[i][j][3]);
      *(ushort4*)(C + (size_t)m * 12288 + n) = o;
    }
  }
}

// ---------------------------------------------------------------------------
// mm1_bt: G = projb @ WEb^T. Tile 128m x 64n, BK=64 dbuf, 48 KB LDS;
// grid 8x64 = 512 = 2/CU exact. mfma(a,b): lane regs span k (G's contiguous
// dim) -> ushort4 scatter into bf16 G[s1][s2][16], guarded < 500.
// ---------------------------------------------------------------------------
__global__ __launch_bounds__(256, 2) void mm1_bt(const ushort_t* __restrict__ A,
                                                 const ushort_t* __restrict__ Bm,
                                                 ushort_t* __restrict__ G) {
  __shared__ ushort_t As[2][2][128 * 32];  // 32 KB
  __shared__ ushort_t Bs[2][2][64 * 32];   // 16 KB
  const int tid = threadIdx.x;
  const int wave = tid >> 6, lane = tid & 63;
  const int m0 = blockIdx.y * 128, n0 = blockIdx.x * 64;
  const int wm = (wave & 1) * 64, wn = (wave >> 1) * 32;
  const int col = lane & 15, quad = lane >> 4;

  floatx4 acc[4][2];
#pragma unroll
  for (int i = 0; i < 4; i++)
#pragma unroll
    for (int j = 0; j < 2; j++)
#pragma unroll
      for (int e = 0; e < 4; e++) acc[i][j][e] = 0.f;

  const int lrow = lane >> 2, scol = (lane & 3) * 8;
  const ushort_t* ga0 = A + (size_t)(m0 + wave * 32 + lrow) * D_ + scol;
  const ushort_t* gb0 = Bm + (size_t)(n0 + wave * 16 + lrow) * D_ + scol;
  const int aoff = (wave * 32) * 32;
  const int boff = (wave * 16) * 32;

#define ISSUE_TILE1(t_, buf_)                                                  \
  do {                                                                         \
    _Pragma("unroll") for (int s_ = 0; s_ < 2; s_++) {                         \
      const ushort_t* ga = ga0 + (t_)*64 + s_ * 32;                            \
      const ushort_t* gb = gb0 + (t_)*64 + s_ * 32;                            \
      GLD_LDS16(ga, &As[buf_][s_][aoff]);                                      \
      GLD_LDS16(ga + 16 * D_, &As[buf_][s_][aoff + 16 * 32]);                  \
      GLD_LDS16(gb, &Bs[buf_][s_][boff]);                                      \
    }                                                                          \
  } while (0)

  ISSUE_TILE1(0, 0);
  for (int t = 0; t < NT; ++t) {
    const int cur = t & 1;
    if (t + 1 < NT) {
      ISSUE_TILE1(t + 1, cur ^ 1);
      WAIT_VM6;
    } else {
      WAIT_VM0;
    }
    ASM_BARRIER;
#pragma unroll
    for (int s = 0; s < 2; ++s) {
      short8 a[4], b[2];
#pragma unroll
      for (int i = 0; i < 4; i++)
        a[i] = *(const short8*)&As[cur][s][(wm + i * 16 + col) * 32 + quad * 8];
#pragma unroll
      for (int j = 0; j < 2; j++)
        b[j] = *(const short8*)&Bs[cur][s][(wn + j * 16 + col) * 32 + quad * 8];
#pragma unroll
      for (int i = 0; i < 4; i++)
#pragma unroll
        for (int j = 0; j < 2; j++)
          acc[i][j] = __builtin_amdgcn_mfma_f32_16x16x32_bf16(a[i], b[j], acc[i][j], 0, 0, 0);
    }
    ASM_BARRIER;
  }
#undef ISSUE_TILE1

  // G[s1][s2][16] bf16: m = (s1,k); 16x16 m-tile is one s1, k = quad*4+reg
#pragma unroll
  for (int i = 0; i < 4; i++) {
    int s1 = (m0 + wm + i * 16) >> 4;
#pragma unroll
    for (int j = 0; j < 2; j++) {
      int s2 = n0 + wn + j * 16 + col;
      if (s1 < S_ && s2 < S_) {
        ushort4 o;
        o.x = f2bf(acc[i][j][0]); o.y = f2bf(acc[i][j][1]);
        o.z = f2bf(acc[i][j][2]); o.w = f2bf(acc[i][j][3]);
        *(ushort4*)(G + (((size_t)s1 * S_ + s2) << 4) + quad * 4) = o;
      }
    }
  }
}

// ---------------------------------------------------------------------------
// lse_kernel: out[r][k] = logsumexp over valid (p,q) of G[idx1[r,p]][idx2[r,q]][k]
// One block per r (single pass); G is bf16.
// ---------------------------------------------------------------------------
__global__ __launch_bounds__(256) void lse_kernel(const ushort_t* __restrict__ G,
                                                  const int* __restrict__ idx1,
                                                  const int* __restrict__ idx2,
                                                  const float* __restrict__ mask1,
                                                  const float* __restrict__ mask2,
                                                  float* __restrict__ out) {
  const int r = blockIdx.x;
  const int tid = threadIdx.x;
  __shared__ int b1[P_], b2[P_];
  __shared__ int s_len1, s_len2;
  __shared__ float wmx[4][K_], wsum[4][K_];

  if (tid < 64) {
    float mv = mask1[r * P_ + tid];
    unsigned long long bal = __ballot(mv > 0.5f);
    if (tid == 0) s_len1 = (int)__popcll(bal);
    b1[tid] = idx1[r * P_ + tid] * (S_ * K_);
  } else if (tid < 128) {
    int q = tid - 64;
    float mv = mask2[r * P_ + q];
    unsigned long long bal = __ballot(mv > 0.5f);
    if (q == 0) s_len2 = (int)__popcll(bal);
    b2[q] = idx2[r * P_ + q] * K_;
  }
  __syncthreads();
  const int len2 = s_len2;
  const int total = s_len1 * len2;

  float m[K_], s[K_];
#pragma unroll
  for (int k = 0; k < K_; k++) { m[k] = -3.0e38f; s[k] = 0.f; }

  for (int i = tid; i < total; i += 256) {
    int p = i / len2;
    int q = i - p * len2;
    const uint4* g4 = (const uint4*)(G + b1[p] + b2[q]);  // 16 bf16 = 32 B
    uint4 w0 = g4[0], w1 = g4[1];
    unsigned int uu[8] = {w0.x, w0.y, w0.z, w0.w, w1.x, w1.y, w1.z, w1.w};
    float z[K_];
#pragma unroll
    for (int h = 0; h < 8; h++) {
      z[2 * h + 0] = __uint_as_float(uu[h] << 16);
      z[2 * h + 1] = __uint_as_float(uu[h] & 0xffff0000u);
    }
#pragma unroll
    for (int k = 0; k < K_; k++) {
      float zk = z[k];
      float M2 = fmaxf(m[k], zk);
      s[k] = s[k] * __expf(m[k] - M2) + __expf(zk - M2);
      m[k] = M2;
    }
  }

#pragma unroll
  for (int off = 1; off < 64; off <<= 1) {
#pragma unroll
    for (int k = 0; k < K_; k++) {
      float mo = __shfl_xor(m[k], off, 64);
      float so = __shfl_xor(s[k], off, 64);
      float M2 = fmaxf(m[k], mo);
      s[k] = s[k] * __expf(m[k] - M2) + so * __expf(mo - M2);
      m[k] = M2;
    }
  }
  const int wave = tid >> 6, lane = tid & 63;
  if (lane == 0) {
#pragma unroll
    for (int k = 0; k < K_; k++) { wmx[wave][k] = m[k]; wsum[wave][k] = s[k]; }
  }
  __syncthreads();
  if (tid < K_) {
    float M = -3.0e38f, Ssum = 0.f;
#pragma unroll
    for (int w = 0; w < 4; w++) {
      float mo = wmx[w][tid], so = wsum[w][tid];
      float M2 = fmaxf(M, mo);
      Ssum = Ssum * __expf(M - M2) + so * __expf(mo - M2);
      M = M2;
    }
    out[r * K_ + tid] = M + __logf(Ssum);
  }
}

// ---------------------------------------------------------------------------
extern "C" void kernel_launch(void* const* d_in, const int* in_sizes, int n_in,
                              void* d_out, int out_size, void* d_ws, size_t ws_size,
                              hipStream_t stream) {
  const float* WE    = (const float*)d_in[0];  // [500][768]
  const float* W     = (const float*)d_in[1];  // [768][16][768]
  const int*   idx1  = (const int*)d_in[2];
  const int*   idx2  = (const int*)d_in[3];
  const float* mask1 = (const float*)d_in[4];
  const float* mask2 = (const float*)d_in[5];
  float* out = (float*)d_out;                  // [256][16]

  // workspace: WEb [512][768] bf16 | Wt [12288][768] bf16 |
  //            projb [512][12288] bf16 (== [8192][768]) | G [500][500][16] bf16
  ushort_t* WEb   = (ushort_t*)d_ws;
  ushort_t* Wt    = WEb + (size_t)512 * 768;
  ushort_t* projb = Wt + (size_t)12288 * 768;
  ushort_t* G     = projb + (size_t)8192 * 768;
  // total ~40.4 MB, 16B-aligned throughout

  prep<<<384 + 2304, 256, 0, stream>>>(WE, W, WEb, Wt);
  // proj[s][(k,e)] = WEb @ Wt^T : M=512, N=12288, tile 128x128, 384 blocks
  mm0_bt<<<dim3(96, 4), 256, 0, stream>>>(WEb, Wt, projb);
  // G[(s1,k)][s2] = projb @ WEb^T : M=8192, N=512, tile 128x64, 512 blocks
  mm1_bt<<<dim3(8, 64), 256, 0, stream>>>(projb, WEb, G);
  lse_kernel<<<R_, 256, 0, stream>>>(G, idx1, idx2, mask1, mask2, out);
}